// Round 6
// baseline (455.815 us; speedup 1.0000x reference)
//
#include <hip/hip_runtime.h>
#include <hip/hip_fp16.h>
#include <cstdint>
#include <cstddef>

#define D 128
#define NAGG 2048
#define SCAN_BLOCKS 256

// ---------------- graph build ----------------
// edge_index arrives as int32: ei[0..E-1] = src, ei[E..2E-1] = dst.

__global__ void count_kernel(const int* __restrict__ ei, int* __restrict__ counts, int E) {
  for (int e = blockIdx.x * blockDim.x + threadIdx.x; e < E; e += gridDim.x * blockDim.x) {
    int d = ei[(size_t)E + e];
    atomicAdd(&counts[d], 1);
  }
}

// ---- three-phase exclusive scan of counts -> row_ptr (+ cursor copy, + dinv) ----

__global__ __launch_bounds__(256) void scan1_kernel(const int* __restrict__ counts,
                                                    int* __restrict__ blocksums, int N) {
  __shared__ int red[256];
  const int b = blockIdx.x, t = threadIdx.x;
  const int chunk = (N + SCAN_BLOCKS - 1) / SCAN_BLOCKS;
  const int lo = b * chunk, hi = min(lo + chunk, N);
  int s = 0;
  for (int i = lo + t; i < hi; i += 256) s += counts[i];
  red[t] = s;
  __syncthreads();
  for (int off = 128; off > 0; off >>= 1) {
    if (t < off) red[t] += red[t + off];
    __syncthreads();
  }
  if (t == 0) blocksums[b] = red[0];
}

__global__ __launch_bounds__(256) void scan2_kernel(int* __restrict__ blocksums) {
  __shared__ int part[256];
  const int t = threadIdx.x;
  part[t] = blocksums[t];
  __syncthreads();
  for (int off = 1; off < 256; off <<= 1) {
    int v = part[t];
    int u = (t >= off) ? part[t - off] : 0;
    __syncthreads();
    part[t] = v + u;
    __syncthreads();
  }
  blocksums[t] = (t == 0) ? 0 : part[t - 1];  // exclusive
}

__global__ __launch_bounds__(256) void scan3_kernel(const int* __restrict__ counts,
                                                    const int* __restrict__ blocksums,
                                                    int* __restrict__ row_ptr,
                                                    int* __restrict__ cursor,
                                                    float* __restrict__ dinv, int N) {
  __shared__ int tsum[256];
  const int b = blockIdx.x, t = threadIdx.x;
  const int chunk = (N + SCAN_BLOCKS - 1) / SCAN_BLOCKS;
  const int lo = b * chunk, hi = min(lo + chunk, N);
  const int tchunk = (chunk + 255) >> 8;
  const int tlo = lo + t * tchunk, thi = min(tlo + tchunk, hi);
  int s = 0;
  for (int i = tlo; i < thi; i++) s += counts[i];
  tsum[t] = s;
  __syncthreads();
  for (int off = 1; off < 256; off <<= 1) {
    int v = tsum[t];
    int u = (t >= off) ? tsum[t - off] : 0;
    __syncthreads();
    tsum[t] = v + u;
    __syncthreads();
  }
  int run = blocksums[b] + ((t == 0) ? 0 : tsum[t - 1]);
  for (int i = tlo; i < thi; i++) {
    int c = counts[i];
    row_ptr[i] = run; cursor[i] = run; run += c;
    dinv[i] = rsqrtf((float)c + 1.0f);
  }
  if (b == SCAN_BLOCKS - 1 && t == 255) row_ptr[N] = blocksums[b] + tsum[255];
}

// R5: plain scatter store col[pos]=s caused 53MB HBM writes (partial-line
// write-miss no-allocate => 16x amplification, 61us). atomicExch executes
// in-L2 with allocation (evidence: count_kernel's atomics never hot).

__global__ void fill_kernel(const int* __restrict__ ei, int* __restrict__ cursor,
                            int* __restrict__ col, int E) {
  for (int e = blockIdx.x * blockDim.x + threadIdx.x; e < E; e += gridDim.x * blockDim.x) {
    int s = ei[e];
    int d = ei[(size_t)E + e];
    int pos = atomicAdd(&cursor[d], 1);
    atomicExch(&col[pos], s);
  }
}

// ---------------- GEMM: hp16[r][c] = (half) dinv[r] * sum_k T(A[r][k]) * W[k][c] ----------------
// T = BN+ReLU of previous layer (identity when scale==nullptr). fp32 VALU math,
// fp16 output. Templated input type: L0 reads x fp32, L1/L2 read y fp16.

template <typename T>
__device__ inline float4 load4f(const T* p);
template <>
__device__ inline float4 load4f<float>(const float* p) { return *(const float4*)p; }
template <>
__device__ inline float4 load4f<__half>(const __half* p) {
  float2 a = __half22float2(*(const __half2*)p);
  float2 b = __half22float2(*(const __half2*)(p + 2));
  return make_float4(a.x, a.y, b.x, b.y);
}

template <typename T>
__global__ __launch_bounds__(256) void gemm_kernel(
    const T* __restrict__ A, const float* __restrict__ Wm,
    const float* __restrict__ scale, const float* __restrict__ shift,
    const float* __restrict__ rowscale, __half* __restrict__ out, int M) {
  __shared__ float At[32][132];   // [kk][row], pad 128->132
  __shared__ float Wl[32][128];   // [kk][col]
  const int tid = threadIdx.x;
  const int tr = tid >> 4;        // 0..15 -> rows tr*8..tr*8+7
  const int tc = tid & 15;        // 0..15 -> cols tc*4..+3 and tc*4+64..+67
  const int bm = blockIdx.x * 128;

  float acc[8][8];
#pragma unroll
  for (int r = 0; r < 8; r++)
#pragma unroll
    for (int c = 0; c < 8; c++) acc[r][c] = 0.f;

  for (int k0 = 0; k0 < 128; k0 += 32) {
    __syncthreads();
#pragma unroll
    for (int i = 0; i < 4; i++) {
      int idx = tid + i * 256;
      int row = idx >> 3;
      int kk = (idx & 7) << 2;
      int gr = bm + row;
      float4 v = make_float4(0.f, 0.f, 0.f, 0.f);
      if (gr < M) {
        v = load4f(A + (size_t)gr * D + k0 + kk);
        if (scale) {
          int c = k0 + kk;
          v.x = fmaxf(fmaf(v.x, scale[c + 0], shift[c + 0]), 0.f);
          v.y = fmaxf(fmaf(v.y, scale[c + 1], shift[c + 1]), 0.f);
          v.z = fmaxf(fmaf(v.z, scale[c + 2], shift[c + 2]), 0.f);
          v.w = fmaxf(fmaf(v.w, scale[c + 3], shift[c + 3]), 0.f);
        }
      }
      At[kk + 0][row] = v.x; At[kk + 1][row] = v.y;
      At[kk + 2][row] = v.z; At[kk + 3][row] = v.w;
    }
#pragma unroll
    for (int i = 0; i < 4; i++) {
      int idx = tid + i * 256;
      int kk = idx >> 5;
      int c4 = (idx & 31) << 2;
      *(float4*)&Wl[kk][c4] = *(const float4*)(Wm + (size_t)(k0 + kk) * D + c4);
    }
    __syncthreads();

#pragma unroll 4
    for (int kk = 0; kk < 32; kk++) {
      float4 alo = *(const float4*)&At[kk][tr * 8];
      float4 ahi = *(const float4*)&At[kk][tr * 8 + 4];
      float4 blo = *(const float4*)&Wl[kk][tc * 4];
      float4 bhi = *(const float4*)&Wl[kk][tc * 4 + 64];
      float a[8] = {alo.x, alo.y, alo.z, alo.w, ahi.x, ahi.y, ahi.z, ahi.w};
      float b[8] = {blo.x, blo.y, blo.z, blo.w, bhi.x, bhi.y, bhi.z, bhi.w};
#pragma unroll
      for (int r = 0; r < 8; r++)
#pragma unroll
        for (int c = 0; c < 8; c++) acc[r][c] = fmaf(a[r], b[c], acc[r][c]);
    }
  }

#pragma unroll
  for (int r = 0; r < 8; r++) {
    int gr = bm + tr * 8 + r;
    if (gr < M) {
      float dv = rowscale[gr];
      __half2 h0 = __floats2half2_rn(acc[r][0] * dv, acc[r][1] * dv);
      __half2 h1 = __floats2half2_rn(acc[r][2] * dv, acc[r][3] * dv);
      __half2 h2 = __floats2half2_rn(acc[r][4] * dv, acc[r][5] * dv);
      __half2 h3 = __floats2half2_rn(acc[r][6] * dv, acc[r][7] * dv);
      __half2* p0 = (__half2*)(out + (size_t)gr * D + tc * 4);
      __half2* p1 = (__half2*)(out + (size_t)gr * D + tc * 4 + 64);
      p0[0] = h0; p0[1] = h1;
      p1[0] = h2; p1[1] = h3;
    }
  }
}

// ---------------- aggregation: y[n] = dinv[n]*(hp[n] + sum_{s in N(n)} hp[s]) + bias ----------------
// hp fp16 (pre-scaled by dinv), y written fp16. fp32 accumulate + stats.

__global__ __launch_bounds__(256) void agg_kernel(
    const __half* __restrict__ hp, const int* __restrict__ row_ptr, const int* __restrict__ col,
    const float* __restrict__ dinv, const float* __restrict__ bias,
    __half* __restrict__ y, float* __restrict__ pstats, int M) {
  const int tid = threadIdx.x;
  const int wave = tid >> 6;
  const int lane = tid & 63;
  const float bx = bias[lane * 2];
  const float by = bias[lane * 2 + 1];
  float sx = 0.f, sy = 0.f, qx = 0.f, qy = 0.f;

  for (int n = blockIdx.x * 4 + wave; n < M; n += gridDim.x * 4) {
    const int beg = row_ptr[n];
    const int end = row_ptr[n + 1];
    const float dn = dinv[n];
    float2 self = __half22float2(*(const __half2*)(hp + (size_t)n * D + lane * 2));
    float ax = self.x, ay = self.y;
#pragma unroll 4
    for (int e = beg; e < end; e++) {
      int s = col[e];
      float2 hv = __half22float2(*(const __half2*)(hp + (size_t)s * D + lane * 2));
      ax += hv.x; ay += hv.y;
    }
    ax = fmaf(ax, dn, bx);
    ay = fmaf(ay, dn, by);
    *(__half2*)(y + (size_t)n * D + lane * 2) = __floats2half2_rn(ax, ay);
    sx += ax; sy += ay;
    qx = fmaf(ax, ax, qx); qy = fmaf(ay, ay, qy);
  }

  __shared__ float ps[4][128];
  ps[wave][lane * 2] = sx; ps[wave][lane * 2 + 1] = sy;
  __syncthreads();
  if (tid < 128) {
    float s = ps[0][tid] + ps[1][tid] + ps[2][tid] + ps[3][tid];
    pstats[(size_t)blockIdx.x * 256 + tid] = s;
  }
  __syncthreads();
  ps[wave][lane * 2] = qx; ps[wave][lane * 2 + 1] = qy;
  __syncthreads();
  if (tid < 128) {
    float s = ps[0][tid] + ps[1][tid] + ps[2][tid] + ps[3][tid];
    pstats[(size_t)blockIdx.x * 256 + 128 + tid] = s;
  }
}

// ---------------- BN param reduce: one block per column ----------------

__global__ void bnred_kernel(const float* __restrict__ pstats, const float* __restrict__ g,
                             const float* __restrict__ be, float* __restrict__ scale,
                             float* __restrict__ shift, float invN) {
  const int c = blockIdx.x;
  const int tid = threadIdx.x;
  float s = 0.f, q = 0.f;
  for (int b = tid; b < NAGG; b += 256) {
    s += pstats[(size_t)b * 256 + c];
    q += pstats[(size_t)b * 256 + 128 + c];
  }
  __shared__ float rs[256], rq[256];
  rs[tid] = s; rq[tid] = q;
  __syncthreads();
  for (int off = 128; off > 0; off >>= 1) {
    if (tid < off) { rs[tid] += rs[tid + off]; rq[tid] += rq[tid + off]; }
    __syncthreads();
  }
  if (tid == 0) {
    float mean = rs[0] * invN;
    float var = rq[0] * invN - mean * mean;
    float sc = g[c] * rsqrtf(var + 1e-5f);
    scale[c] = sc;
    shift[c] = be[c] - mean * sc;
  }
}

// ---------------- mean-pool of relu(bn(y)) -> per-block partials ----------------

__global__ __launch_bounds__(256) void pool_kernel(
    const __half* __restrict__ y, const float* __restrict__ scale, const float* __restrict__ shift,
    float* __restrict__ ppool, int M) {
  const int tid = threadIdx.x;
  const int wave = tid >> 6;
  const int lane = tid & 63;
  const float scx = scale[lane * 2], scy = scale[lane * 2 + 1];
  const float shx = shift[lane * 2], shy = shift[lane * 2 + 1];
  float sx = 0.f, sy = 0.f;
  for (int n = blockIdx.x * 4 + wave; n < M; n += gridDim.x * 4) {
    float2 v = __half22float2(*(const __half2*)(y + (size_t)n * D + lane * 2));
    sx += fmaxf(fmaf(v.x, scx, shx), 0.f);
    sy += fmaxf(fmaf(v.y, scy, shy), 0.f);
  }
  __shared__ float ps[4][128];
  ps[wave][lane * 2] = sx; ps[wave][lane * 2 + 1] = sy;
  __syncthreads();
  if (tid < 128) {
    float s = ps[0][tid] + ps[1][tid] + ps[2][tid] + ps[3][tid];
    ppool[(size_t)blockIdx.x * 128 + tid] = s;
  }
}

__global__ void poolred_kernel(const float* __restrict__ ppool, float* __restrict__ pooled, float invN) {
  const int c = blockIdx.x;
  const int tid = threadIdx.x;
  float s = 0.f;
  for (int b = tid; b < NAGG; b += 256) s += ppool[(size_t)b * 128 + c];
  __shared__ float rs[256];
  rs[tid] = s;
  __syncthreads();
  for (int off = 128; off > 0; off >>= 1) {
    if (tid < off) rs[tid] += rs[tid + off];
    __syncthreads();
  }
  if (tid == 0) pooled[c] = rs[0] * invN;
}

// ---------------- classifier head ----------------

__global__ void mlp_kernel(const float* __restrict__ pooled,
                           const float* __restrict__ cW1, const float* __restrict__ cb1,
                           const float* __restrict__ cW2, const float* __restrict__ cb2,
                           float* __restrict__ outp) {
  __shared__ float pl[128];
  __shared__ float h1[64];
  const int tid = threadIdx.x;
  if (tid < 128) pl[tid] = pooled[tid];
  __syncthreads();
  if (tid < 64) {
    float s = cb1[tid];
    for (int k = 0; k < 128; k++) s = fmaf(pl[k], cW1[(size_t)k * 64 + tid], s);
    h1[tid] = fmaxf(s, 0.f);
  }
  __syncthreads();
  if (tid < 5) {
    float s = cb2[tid];
    for (int k = 0; k < 64; k++) s = fmaf(h1[k], cW2[(size_t)k * 5 + tid], s);
    outp[tid] = s;
  }
}

// ---------------- launch ----------------

extern "C" void kernel_launch(void* const* d_in, const int* in_sizes, int n_in,
                              void* d_out, int out_size, void* d_ws, size_t ws_size,
                              hipStream_t stream) {
  const float* x = (const float*)d_in[0];
  const int* ei = (const int*)d_in[1];
  const float* Wm[3] = {(const float*)d_in[2], (const float*)d_in[6], (const float*)d_in[10]};
  const float* bb[3] = {(const float*)d_in[3], (const float*)d_in[7], (const float*)d_in[11]};
  const float* gg[3] = {(const float*)d_in[4], (const float*)d_in[8], (const float*)d_in[12]};
  const float* be[3] = {(const float*)d_in[5], (const float*)d_in[9], (const float*)d_in[13]};
  const float* cW1 = (const float*)d_in[14];
  const float* cb1 = (const float*)d_in[15];
  const float* cW2 = (const float*)d_in[16];
  const float* cb2 = (const float*)d_in[17];
  float* outp = (float*)d_out;

  const int N = in_sizes[0] / D;
  const int E = in_sizes[1] / 2;

  char* wsp = (char*)d_ws;
  size_t off = 0;
  auto alloc = [&](size_t bytes) -> char* {
    char* p = wsp + off;
    off += (bytes + 255) & ~(size_t)255;
    return p;
  };
  int* counts   = (int*)alloc((size_t)N * 4);
  float* dinv   = (float*)alloc((size_t)N * 4);
  int* row_ptr  = (int*)alloc((size_t)(N + 1) * 4);
  int* cursor   = (int*)alloc((size_t)N * 4);
  int* col      = (int*)alloc((size_t)E * 4);
  __half* h     = (__half*)alloc((size_t)N * D * 2);
  __half* y     = (__half*)alloc((size_t)N * D * 2);
  float* pstats = (float*)alloc((size_t)NAGG * 256 * 4);
  float* ppool  = (float*)alloc((size_t)NAGG * 128 * 4);
  float* sc     = (float*)alloc(3 * 128 * 4);
  float* sh     = (float*)alloc(3 * 128 * 4);
  float* pooled = (float*)alloc(128 * 4);
  int* blocksums= (int*)alloc(SCAN_BLOCKS * 4);
  (void)ws_size; (void)n_in; (void)out_size;

  hipMemsetAsync(counts, 0, (size_t)N * 4, stream);
  count_kernel<<<2048, 256, 0, stream>>>(ei, counts, E);
  scan1_kernel<<<SCAN_BLOCKS, 256, 0, stream>>>(counts, blocksums, N);
  scan2_kernel<<<1, 256, 0, stream>>>(blocksums);
  scan3_kernel<<<SCAN_BLOCKS, 256, 0, stream>>>(counts, blocksums, row_ptr, cursor, dinv, N);
  fill_kernel<<<2048, 256, 0, stream>>>(ei, cursor, col, E);

  const int gblocks = (N + 127) / 128;
  const float invN = 1.0f / (float)N;
  for (int L = 0; L < 3; L++) {
    const float* scl = (L == 0) ? nullptr : sc + (size_t)(L - 1) * 128;
    const float* shf = (L == 0) ? nullptr : sh + (size_t)(L - 1) * 128;
    if (L == 0)
      gemm_kernel<float><<<gblocks, 256, 0, stream>>>(x, Wm[L], scl, shf, dinv, h, N);
    else
      gemm_kernel<__half><<<gblocks, 256, 0, stream>>>(y, Wm[L], scl, shf, dinv, h, N);
    agg_kernel<<<NAGG, 256, 0, stream>>>(h, row_ptr, col, dinv, bb[L], y, pstats, N);
    bnred_kernel<<<128, 256, 0, stream>>>(pstats, gg[L], be[L], sc + (size_t)L * 128,
                                          sh + (size_t)L * 128, invN);
  }
  pool_kernel<<<NAGG, 256, 0, stream>>>(y, sc + 256, sh + 256, ppool, N);
  poolred_kernel<<<128, 256, 0, stream>>>(ppool, pooled, invN);
  mlp_kernel<<<1, 128, 0, stream>>>(pooled, cW1, cb1, cW2, cb2, outp);
}

// Round 7
// 421.017 us; speedup vs baseline: 1.0827x; 1.0827x over previous
//
#include <hip/hip_runtime.h>
#include <hip/hip_fp16.h>
#include <cstdint>
#include <cstddef>

#define D 128
#define NAGG 2048
#define SCAN_BLOCKS 256

using f16x4 = __attribute__((ext_vector_type(4))) _Float16;
using f32x4 = __attribute__((ext_vector_type(4))) float;

// 16B-slot XOR swizzle: spreads 8 consecutive rows (256B stride) across 8
// distinct 16B slots -> ds_read_b64 per-frag conflicts drop to 2-way (free).
__device__ __forceinline__ int swz(int row, int byte) {
  return row * 256 + (((byte)&0xF0) ^ ((row & 7) << 4)) + ((byte)&0x0F);
}

// ---------------- graph build ----------------
// edge_index arrives as int32: ei[0..E-1] = src, ei[E..2E-1] = dst.

__global__ void count_kernel(const int* __restrict__ ei, int* __restrict__ counts, int E) {
  for (int e = blockIdx.x * blockDim.x + threadIdx.x; e < E; e += gridDim.x * blockDim.x) {
    int d = ei[(size_t)E + e];
    atomicAdd(&counts[d], 1);
  }
}

__global__ __launch_bounds__(256) void scan1_kernel(const int* __restrict__ counts,
                                                    int* __restrict__ blocksums, int N) {
  __shared__ int red[256];
  const int b = blockIdx.x, t = threadIdx.x;
  const int chunk = (N + SCAN_BLOCKS - 1) / SCAN_BLOCKS;
  const int lo = b * chunk, hi = min(lo + chunk, N);
  int s = 0;
  for (int i = lo + t; i < hi; i += 256) s += counts[i];
  red[t] = s;
  __syncthreads();
  for (int off = 128; off > 0; off >>= 1) {
    if (t < off) red[t] += red[t + off];
    __syncthreads();
  }
  if (t == 0) blocksums[b] = red[0];
}

__global__ __launch_bounds__(256) void scan2_kernel(int* __restrict__ blocksums) {
  __shared__ int part[256];
  const int t = threadIdx.x;
  part[t] = blocksums[t];
  __syncthreads();
  for (int off = 1; off < 256; off <<= 1) {
    int v = part[t];
    int u = (t >= off) ? part[t - off] : 0;
    __syncthreads();
    part[t] = v + u;
    __syncthreads();
  }
  blocksums[t] = (t == 0) ? 0 : part[t - 1];  // exclusive
}

__global__ __launch_bounds__(256) void scan3_kernel(const int* __restrict__ counts,
                                                    const int* __restrict__ blocksums,
                                                    int* __restrict__ row_ptr,
                                                    int* __restrict__ cursor,
                                                    float* __restrict__ dinv, int N) {
  __shared__ int tsum[256];
  const int b = blockIdx.x, t = threadIdx.x;
  const int chunk = (N + SCAN_BLOCKS - 1) / SCAN_BLOCKS;
  const int lo = b * chunk, hi = min(lo + chunk, N);
  const int tchunk = (chunk + 255) >> 8;
  const int tlo = lo + t * tchunk, thi = min(tlo + tchunk, hi);
  int s = 0;
  for (int i = tlo; i < thi; i++) s += counts[i];
  tsum[t] = s;
  __syncthreads();
  for (int off = 1; off < 256; off <<= 1) {
    int v = tsum[t];
    int u = (t >= off) ? tsum[t - off] : 0;
    __syncthreads();
    tsum[t] = v + u;
    __syncthreads();
  }
  int run = blocksums[b] + ((t == 0) ? 0 : tsum[t - 1]);
  for (int i = tlo; i < thi; i++) {
    int c = counts[i];
    row_ptr[i] = run; cursor[i] = run; run += c;
    dinv[i] = rsqrtf((float)c + 1.0f);
  }
  if (b == SCAN_BLOCKS - 1 && t == 255) row_ptr[N] = blocksums[b] + tsum[255];
}

// R6: atomicExch did NOT allocate in L2 (WRITE_SIZE unchanged 50MB, dur 61->73).
// Reverted to plain store; the 64B-granule write amplification stands for now.

__global__ void fill_kernel(const int* __restrict__ ei, int* __restrict__ cursor,
                            int* __restrict__ col, int E) {
  for (int e = blockIdx.x * blockDim.x + threadIdx.x; e < E; e += gridDim.x * blockDim.x) {
    int s = ei[e];
    int d = ei[(size_t)E + e];
    int pos = atomicAdd(&cursor[d], 1);
    col[pos] = s;
  }
}

// ---------------- W transpose+convert: Wt[L][col][k] = (f16) W_L[k][col] ----------------

__global__ void wconv_kernel(const float* __restrict__ W0, const float* __restrict__ W1,
                             const float* __restrict__ W2, __half* __restrict__ Wt) {
  int i = blockIdx.x * 256 + threadIdx.x;  // 0..49151
  if (i >= 3 * 128 * 128) return;
  int L = i >> 14, r = i & 16383;
  int col = r >> 7, k = r & 127;
  const float* W = (L == 0) ? W0 : (L == 1) ? W1 : W2;
  Wt[i] = __float2half(W[k * 128 + col]);
}

// ---------------- MFMA GEMM: h[r][c] = (half) dinv[r] * sum_k T(A[r][k]) * W[k][c] ----
// R6: fp32 VALU gemm was ~50us each (no fp32 MFMA on CDNA4); fp16 intermediates
// already validated (R5) -> v_mfma_f32_16x16x16f16 (classic documented layout:
// A row=lane&15,k=(lane>>4)*4+j; B col=lane&15 same k; D col=lane&15,row=(lane>>4)*4+reg).
// Whole-K LDS staging (A 32KB + Wt 32KB), BN+ReLU fused into A-staging.

template <typename T>
__global__ __launch_bounds__(256, 2) void gemm_mfma_kernel(
    const T* __restrict__ A, const __half* __restrict__ Wt,
    const float* __restrict__ scale, const float* __restrict__ shift,
    const float* __restrict__ dinv, __half* __restrict__ out, int M) {
  __shared__ __align__(16) char asb[128 * 256];  // A tile [row][k] f16, swizzled
  __shared__ __align__(16) char bsb[128 * 256];  // Wt tile [col][k] f16, swizzled
  const int tid = threadIdx.x;
  const int bm = blockIdx.x * 128;

  // ---- stage A (convert to f16; BN+ReLU when scale != null) ----
  if constexpr (sizeof(T) == 4) {  // fp32 x input, no BN
    for (int i = 0; i < 16; i++) {
      int g = tid + i * 256;        // 0..4095 float4 groups
      int row = g >> 5;
      int c4 = (g & 31) << 2;       // k-col 0..124
      int gr = bm + row;
      float4 v = make_float4(0.f, 0.f, 0.f, 0.f);
      if (gr < M) v = *(const float4*)(A + (size_t)gr * D + c4);
      union { float2 f2; __half h[4]; } u;
      u.h[0] = __float2half(v.x); u.h[1] = __float2half(v.y);
      u.h[2] = __float2half(v.z); u.h[3] = __float2half(v.w);
      *(float2*)(asb + swz(row, c4 * 2)) = u.f2;
    }
  } else {  // fp16 y input, fused BN+ReLU
    for (int i = 0; i < 8; i++) {
      int g = tid + i * 256;        // 0..2047 16B chunks
      int row = g >> 4;
      int c8 = (g & 15) << 3;       // k-col 0..120
      int gr = bm + row;
      union { float4 f4; __half h[8]; } u;
      if (gr < M) {
        u.f4 = *(const float4*)((const __half*)A + (size_t)gr * D + c8);
        float4 s0 = *(const float4*)&scale[c8];
        float4 s1 = *(const float4*)&scale[c8 + 4];
        float4 b0 = *(const float4*)&shift[c8];
        float4 b1 = *(const float4*)&shift[c8 + 4];
        const float* sp = &s0.x; const float* bp = &b0.x;
#pragma unroll
        for (int j = 0; j < 4; j++)
          u.h[j] = __float2half(fmaxf(fmaf(__half2float(u.h[j]), sp[j], bp[j]), 0.f));
        sp = &s1.x; bp = &b1.x;
#pragma unroll
        for (int j = 0; j < 4; j++)
          u.h[4 + j] = __float2half(fmaxf(fmaf(__half2float(u.h[4 + j]), sp[j], bp[j]), 0.f));
      } else {
        u.f4 = make_float4(0.f, 0.f, 0.f, 0.f);
      }
      *(float4*)(asb + swz(row, c8 * 2)) = u.f4;
    }
  }
  // ---- stage Wt (already [col][k] f16 in global) ----
  for (int i = 0; i < 8; i++) {
    int g = tid + i * 256;          // 0..2047 16B chunks
    int row = g >> 3;
    int sl = (g & 7) << 4;
    *(float4*)(bsb + swz(row, sl)) = *(const float4*)((const char*)Wt + (size_t)g * 16);
  }
  __syncthreads();

  // ---- MFMA main loop: wave w owns rows [w*32, w*32+32) x all 128 cols ----
  const int lane = tid & 63;
  const int w = tid >> 6;
  const int l15 = lane & 15;
  const int khalf = lane >> 4;      // 0..3

  f32x4 acc[2][8];
#pragma unroll
  for (int m = 0; m < 2; m++)
#pragma unroll
    for (int n = 0; n < 8; n++) acc[m][n] = (f32x4){0.f, 0.f, 0.f, 0.f};

#pragma unroll
  for (int ks = 0; ks < 8; ks++) {
    int kbyte = ks * 32 + khalf * 8;
    f16x4 a0 = *(const f16x4*)(asb + swz(w * 32 + l15, kbyte));
    f16x4 a1 = *(const f16x4*)(asb + swz(w * 32 + 16 + l15, kbyte));
#pragma unroll
    for (int n = 0; n < 8; n++) {
      f16x4 b = *(const f16x4*)(bsb + swz(n * 16 + l15, kbyte));
      acc[0][n] = __builtin_amdgcn_mfma_f32_16x16x16f16(a0, b, acc[0][n], 0, 0, 0);
      acc[1][n] = __builtin_amdgcn_mfma_f32_16x16x16f16(a1, b, acc[1][n], 0, 0, 0);
    }
  }

  // ---- epilogue: out[row][col] = half(acc * dinv[row]) ----
#pragma unroll
  for (int m = 0; m < 2; m++) {
    int base_r = bm + w * 32 + m * 16 + khalf * 4;
    float dv[4];
#pragma unroll
    for (int j = 0; j < 4; j++) dv[j] = (base_r + j < M) ? dinv[base_r + j] : 0.f;
#pragma unroll
    for (int n = 0; n < 8; n++) {
      int colg = n * 16 + l15;
#pragma unroll
      for (int j = 0; j < 4; j++) {
        int r = base_r + j;
        if (r < M) out[(size_t)r * D + colg] = __float2half(acc[m][n][j] * dv[j]);
      }
    }
  }
}

// ---------------- aggregation: y[n] = dinv[n]*(hp[n] + sum_{s in N(n)} hp[s]) + bias ----
// hp fp16 (pre-scaled by dinv), y written fp16. fp32 accumulate + stats.

__global__ __launch_bounds__(256) void agg_kernel(
    const __half* __restrict__ hp, const int* __restrict__ row_ptr, const int* __restrict__ col,
    const float* __restrict__ dinv, const float* __restrict__ bias,
    __half* __restrict__ y, float* __restrict__ pstats, int M) {
  const int tid = threadIdx.x;
  const int wave = tid >> 6;
  const int lane = tid & 63;
  const float bx = bias[lane * 2];
  const float by = bias[lane * 2 + 1];
  float sx = 0.f, sy = 0.f, qx = 0.f, qy = 0.f;

  for (int n = blockIdx.x * 4 + wave; n < M; n += gridDim.x * 4) {
    const int beg = row_ptr[n];
    const int end = row_ptr[n + 1];
    const float dn = dinv[n];
    float2 self = __half22float2(*(const __half2*)(hp + (size_t)n * D + lane * 2));
    float ax = self.x, ay = self.y;
#pragma unroll 4
    for (int e = beg; e < end; e++) {
      int s = col[e];
      float2 hv = __half22float2(*(const __half2*)(hp + (size_t)s * D + lane * 2));
      ax += hv.x; ay += hv.y;
    }
    ax = fmaf(ax, dn, bx);
    ay = fmaf(ay, dn, by);
    *(__half2*)(y + (size_t)n * D + lane * 2) = __floats2half2_rn(ax, ay);
    sx += ax; sy += ay;
    qx = fmaf(ax, ax, qx); qy = fmaf(ay, ay, qy);
  }

  __shared__ float ps[4][128];
  ps[wave][lane * 2] = sx; ps[wave][lane * 2 + 1] = sy;
  __syncthreads();
  if (tid < 128) {
    float s = ps[0][tid] + ps[1][tid] + ps[2][tid] + ps[3][tid];
    pstats[(size_t)blockIdx.x * 256 + tid] = s;
  }
  __syncthreads();
  ps[wave][lane * 2] = qx; ps[wave][lane * 2 + 1] = qy;
  __syncthreads();
  if (tid < 128) {
    float s = ps[0][tid] + ps[1][tid] + ps[2][tid] + ps[3][tid];
    pstats[(size_t)blockIdx.x * 256 + 128 + tid] = s;
  }
}

// ---------------- BN param reduce ----------------

__global__ void bnred_kernel(const float* __restrict__ pstats, const float* __restrict__ g,
                             const float* __restrict__ be, float* __restrict__ scale,
                             float* __restrict__ shift, float invN) {
  const int c = blockIdx.x;
  const int tid = threadIdx.x;
  float s = 0.f, q = 0.f;
  for (int b = tid; b < NAGG; b += 256) {
    s += pstats[(size_t)b * 256 + c];
    q += pstats[(size_t)b * 256 + 128 + c];
  }
  __shared__ float rs[256], rq[256];
  rs[tid] = s; rq[tid] = q;
  __syncthreads();
  for (int off = 128; off > 0; off >>= 1) {
    if (tid < off) { rs[tid] += rs[tid + off]; rq[tid] += rq[tid + off]; }
    __syncthreads();
  }
  if (tid == 0) {
    float mean = rs[0] * invN;
    float var = rq[0] * invN - mean * mean;
    float sc = g[c] * rsqrtf(var + 1e-5f);
    scale[c] = sc;
    shift[c] = be[c] - mean * sc;
  }
}

// ---------------- mean-pool of relu(bn(y)) ----------------

__global__ __launch_bounds__(256) void pool_kernel(
    const __half* __restrict__ y, const float* __restrict__ scale, const float* __restrict__ shift,
    float* __restrict__ ppool, int M) {
  const int tid = threadIdx.x;
  const int wave = tid >> 6;
  const int lane = tid & 63;
  const float scx = scale[lane * 2], scy = scale[lane * 2 + 1];
  const float shx = shift[lane * 2], shy = shift[lane * 2 + 1];
  float sx = 0.f, sy = 0.f;
  for (int n = blockIdx.x * 4 + wave; n < M; n += gridDim.x * 4) {
    float2 v = __half22float2(*(const __half2*)(y + (size_t)n * D + lane * 2));
    sx += fmaxf(fmaf(v.x, scx, shx), 0.f);
    sy += fmaxf(fmaf(v.y, scy, shy), 0.f);
  }
  __shared__ float ps[4][128];
  ps[wave][lane * 2] = sx; ps[wave][lane * 2 + 1] = sy;
  __syncthreads();
  if (tid < 128) {
    float s = ps[0][tid] + ps[1][tid] + ps[2][tid] + ps[3][tid];
    ppool[(size_t)blockIdx.x * 128 + tid] = s;
  }
}

__global__ void poolred_kernel(const float* __restrict__ ppool, float* __restrict__ pooled, float invN) {
  const int c = blockIdx.x;
  const int tid = threadIdx.x;
  float s = 0.f;
  for (int b = tid; b < NAGG; b += 256) s += ppool[(size_t)b * 128 + c];
  __shared__ float rs[256];
  rs[tid] = s;
  __syncthreads();
  for (int off = 128; off > 0; off >>= 1) {
    if (tid < off) rs[tid] += rs[tid + off];
    __syncthreads();
  }
  if (tid == 0) pooled[c] = rs[0] * invN;
}

// ---------------- classifier head ----------------

__global__ void mlp_kernel(const float* __restrict__ pooled,
                           const float* __restrict__ cW1, const float* __restrict__ cb1,
                           const float* __restrict__ cW2, const float* __restrict__ cb2,
                           float* __restrict__ outp) {
  __shared__ float pl[128];
  __shared__ float h1[64];
  const int tid = threadIdx.x;
  if (tid < 128) pl[tid] = pooled[tid];
  __syncthreads();
  if (tid < 64) {
    float s = cb1[tid];
    for (int k = 0; k < 128; k++) s = fmaf(pl[k], cW1[(size_t)k * 64 + tid], s);
    h1[tid] = fmaxf(s, 0.f);
  }
  __syncthreads();
  if (tid < 5) {
    float s = cb2[tid];
    for (int k = 0; k < 64; k++) s = fmaf(h1[k], cW2[(size_t)k * 5 + tid], s);
    outp[tid] = s;
  }
}

// ---------------- launch ----------------

extern "C" void kernel_launch(void* const* d_in, const int* in_sizes, int n_in,
                              void* d_out, int out_size, void* d_ws, size_t ws_size,
                              hipStream_t stream) {
  const float* x = (const float*)d_in[0];
  const int* ei = (const int*)d_in[1];
  const float* Wm[3] = {(const float*)d_in[2], (const float*)d_in[6], (const float*)d_in[10]};
  const float* bb[3] = {(const float*)d_in[3], (const float*)d_in[7], (const float*)d_in[11]};
  const float* gg[3] = {(const float*)d_in[4], (const float*)d_in[8], (const float*)d_in[12]};
  const float* be[3] = {(const float*)d_in[5], (const float*)d_in[9], (const float*)d_in[13]};
  const float* cW1 = (const float*)d_in[14];
  const float* cb1 = (const float*)d_in[15];
  const float* cW2 = (const float*)d_in[16];
  const float* cb2 = (const float*)d_in[17];
  float* outp = (float*)d_out;

  const int N = in_sizes[0] / D;
  const int E = in_sizes[1] / 2;

  char* wsp = (char*)d_ws;
  size_t off = 0;
  auto alloc = [&](size_t bytes) -> char* {
    char* p = wsp + off;
    off += (bytes + 255) & ~(size_t)255;
    return p;
  };
  int* counts   = (int*)alloc((size_t)N * 4);
  float* dinv   = (float*)alloc((size_t)N * 4);
  int* row_ptr  = (int*)alloc((size_t)(N + 1) * 4);
  int* cursor   = (int*)alloc((size_t)N * 4);
  int* col      = (int*)alloc((size_t)E * 4);
  __half* h     = (__half*)alloc((size_t)N * D * 2);
  __half* y     = (__half*)alloc((size_t)N * D * 2);
  __half* Wt    = (__half*)alloc((size_t)3 * 128 * 128 * 2);
  float* pstats = (float*)alloc((size_t)NAGG * 256 * 4);
  float* ppool  = (float*)alloc((size_t)NAGG * 128 * 4);
  float* sc     = (float*)alloc(3 * 128 * 4);
  float* sh     = (float*)alloc(3 * 128 * 4);
  float* pooled = (float*)alloc(128 * 4);
  int* blocksums= (int*)alloc(SCAN_BLOCKS * 4);
  (void)ws_size; (void)n_in; (void)out_size;

  hipMemsetAsync(counts, 0, (size_t)N * 4, stream);
  wconv_kernel<<<192, 256, 0, stream>>>(Wm[0], Wm[1], Wm[2], Wt);
  count_kernel<<<2048, 256, 0, stream>>>(ei, counts, E);
  scan1_kernel<<<SCAN_BLOCKS, 256, 0, stream>>>(counts, blocksums, N);
  scan2_kernel<<<1, 256, 0, stream>>>(blocksums);
  scan3_kernel<<<SCAN_BLOCKS, 256, 0, stream>>>(counts, blocksums, row_ptr, cursor, dinv, N);
  fill_kernel<<<2048, 256, 0, stream>>>(ei, cursor, col, E);

  const int gblocks = (N + 127) / 128;
  const float invN = 1.0f / (float)N;
  for (int L = 0; L < 3; L++) {
    const float* scl = (L == 0) ? nullptr : sc + (size_t)(L - 1) * 128;
    const float* shf = (L == 0) ? nullptr : sh + (size_t)(L - 1) * 128;
    if (L == 0)
      gemm_mfma_kernel<float><<<gblocks, 256, 0, stream>>>(x, Wt, scl, shf, dinv, h, N);
    else
      gemm_mfma_kernel<__half><<<gblocks, 256, 0, stream>>>(y, Wt + (size_t)L * 16384, scl, shf, dinv, h, N);
    agg_kernel<<<NAGG, 256, 0, stream>>>(h, row_ptr, col, dinv, bb[L], y, pstats, N);
    bnred_kernel<<<128, 256, 0, stream>>>(pstats, gg[L], be[L], sc + (size_t)L * 128,
                                          sh + (size_t)L * 128, invN);
  }
  pool_kernel<<<NAGG, 256, 0, stream>>>(y, sc + 256, sh + 256, ppool, N);
  poolred_kernel<<<128, 256, 0, stream>>>(ppool, pooled, invN);
  mlp_kernel<<<1, 128, 0, stream>>>(pooled, cW1, cb1, cW2, cb2, outp);
}